// Round 7
// baseline (304.329 us; speedup 1.0000x reference)
//
#include <hip/hip_runtime.h>

#define XL 432
#define YL 496
#define CELLS_B (YL * XL)     // 214272 cells per batch
#define PLANE4 (CELLS_B / 4)  // 53568 float4-groups per (b,c) plane
#define BN 4
#define COUT 64
#define PP 32

// canvas tiling: 96 cells/tile, double-buffered LDS pipeline
#define TCELLS 96
#define TPB (CELLS_B / TCELLS)   // 2232 tiles per batch (exact)
#define NTILES (BN * TPB)        // 8928
#define LSTR 100                 // LDS row stride (dwords): %4==0, 400%32=16 -> 2-way (free)
#define CTHREADS 384             // 6 waves; 4 thr/cell phase-1, 16x24 phase-2
#define CBLOCKS 768              // 3 per CU (LDS 51.2 KB)

typedef float v4f __attribute__((ext_vector_type(4)));

// Pass 1: resolve scatter collisions — highest pillar index wins (numpy
// last-write-wins semantics for duplicate (b,y,x) cells).
__global__ __launch_bounds__(256) void winner_kernel(const int* __restrict__ coors,
                                                     int* __restrict__ winner, int M) {
    int m = blockIdx.x * blockDim.x + threadIdx.x;
    if (m >= M) return;
    const int4 c = ((const int4*)coors)[m];
    if (c.w < 0 || c.w >= XL || c.z < 0 || c.z >= YL) return;
    atomicMax(&winner[(c.x * YL + c.z) * XL + c.w], m);
}

// Pass 2 (unchanged from R6): folded 9->64 matvec + BN + ReLU + max-pool.
__global__ __launch_bounds__(256) void pillar_compute(
    const float* __restrict__ pillars, const int* __restrict__ coors,
    const int* __restrict__ nums, const float* __restrict__ W,
    const float* __restrict__ gamma, const float* __restrict__ beta,
    const float* __restrict__ rmean, const float* __restrict__ rvar,
    const int* __restrict__ winner, float* __restrict__ pooled, int M) {
    const int pb   = threadIdx.x >> 6;
    const int lane = threadIdx.x & 63;
    const int m    = blockIdx.x * 4 + pb;

    __shared__ float4 pts[4][PP];

    if (m < M && lane < PP) {
        pts[pb][lane] = ((const float4*)pillars)[m * PP + lane];
    }
    __syncthreads();
    if (m >= M) return;

    const int4 co = ((const int4*)coors)[m];
    const int x = co.w, y = co.z;
    if (x < 0 || x >= XL || y < 0 || y >= YL) return;
    if (winner[(co.x * YL + y) * XL + x] != m) return;

    int num = nums[m];
    if (num < 1) num = 1;
    if (num > PP) num = PP;

    const float scale = gamma[lane] * rsqrtf(rvar[lane] + 1e-3f);
    const float bias  = beta[lane] - rmean[lane] * scale;

    const float w0 = W[lane * 9 + 0], w1 = W[lane * 9 + 1], w2 = W[lane * 9 + 2];
    const float w3 = W[lane * 9 + 3], w4 = W[lane * 9 + 4], w5 = W[lane * 9 + 5];
    const float w6 = W[lane * 9 + 6], w7 = W[lane * 9 + 7], w8 = W[lane * 9 + 8];
    const float cwx = w0 + w4 + w7, cwy = w1 + w5 + w8, cwz = w2 + w6, cww = w3;

    float sx = 0.f, sy = 0.f, sz = 0.f;
    float dmax = -3.0e38f, dmin = 3.0e38f;
    for (int p = 0; p < num; ++p) {
        const float4 q = pts[pb][p];
        sx += q.x; sy += q.y; sz += q.z;
        const float d = q.x * cwx + q.y * cwy + q.z * cwz + q.w * cww;
        dmax = fmaxf(dmax, d);
        dmin = fminf(dmin, d);
    }
    const float inv = 1.0f / (float)num;
    const float xc = (float)x * 0.16f + 0.08f;
    const float yc = (float)y * 0.16f + (0.08f - 39.68f);
    const float C0 = sx * inv * w4 + sy * inv * w5 + sz * inv * w6
                   + xc * w7 + yc * w8;

    const float sel = (scale >= 0.f) ? dmax : dmin;
    float v = (sel - C0) * scale + bias;
    if (num < PP) v = fmaxf(v, bias);
    pooled[m * COUT + lane] = fmaxf(v, 0.f);
}

// Pass 3: persistent double-buffered pipeline. Per tile (96 cells):
//   phase1: 4 thr/cell gather winner row (4 x float4) -> regs
//   ldsWrite: scatter to lds[buf][ch*LSTR+cell] (2 lanes/bank, free)
//   phase2: (chi,xg) stores 4 channels x 16B, NT, full lines
// Pipeline: winner prefetched TWO tiles ahead (gather never waits on a
// fresh winner load); gather for t+1 issues before the barrier so loads
// are in flight while tile t's stores drain.
__global__ __launch_bounds__(CTHREADS) void canvas_kernel(
    const int* __restrict__ winner,     // (BN, YL, XL)
    const float* __restrict__ pooled,   // (M, 64)
    v4f* __restrict__ out4) {           // (BN, 64, PLANE4)
    __shared__ float lds[2][COUT * LSTR];   // 2 x 25600 B

    const int t0   = threadIdx.x;
    const int cell = t0 >> 2;           // 0..95
    const int qq   = t0 & 3;
    const int chi  = t0 / 24;           // 0..15
    const int xg   = t0 - chi * 24;     // 0..23

    int t = blockIdx.x;
    if (t >= NTILES) return;

    // winner address for tile tt
    auto widx = [&](int tt) {
        int b = tt / TPB, ti = tt - b * TPB;
        return b * CELLS_B + ti * TCELLS + cell;
    };

    int w_cur = winner[widx(t)];
    int t1 = t + CBLOCKS;
    int w_nxt = (t1 < NTILES) ? winner[widx(t1)] : -1;

    float4 r[4];
    {
        if (w_cur >= 0) {
            const float4* row = (const float4*)(pooled + (size_t)w_cur * COUT);
            #pragma unroll
            for (int k = 0; k < 4; ++k) r[k] = row[qq + 4 * k];
        } else {
            #pragma unroll
            for (int k = 0; k < 4; ++k) r[k] = make_float4(0.f, 0.f, 0.f, 0.f);
        }
    }

    int buf = 0;
    while (true) {
        // stage current tile's regs into LDS
        #pragma unroll
        for (int k = 0; k < 4; ++k) {
            const int cb = 4 * (qq + 4 * k);
            lds[buf][(cb + 0) * LSTR + cell] = r[k].x;
            lds[buf][(cb + 1) * LSTR + cell] = r[k].y;
            lds[buf][(cb + 2) * LSTR + cell] = r[k].z;
            lds[buf][(cb + 3) * LSTR + cell] = r[k].w;
        }

        // prefetch winner two tiles ahead; gather next tile with the
        // winner loaded last iteration (no dependent wait here)
        const int t2 = t1 + CBLOCKS;
        const int w2 = (t2 < NTILES) ? winner[widx(t2)] : -1;
        const bool have_next = (t1 < NTILES);
        float4 rn[4];
        if (have_next && w_nxt >= 0) {
            const float4* row = (const float4*)(pooled + (size_t)w_nxt * COUT);
            #pragma unroll
            for (int k = 0; k < 4; ++k) rn[k] = row[qq + 4 * k];
        } else {
            #pragma unroll
            for (int k = 0; k < 4; ++k) rn[k] = make_float4(0.f, 0.f, 0.f, 0.f);
        }

        __syncthreads();   // lds[buf] ready; prior reads of lds[buf^1] done

        // store tile t: 4 channels x 16B NT per thread, full-line coalesced
        {
            const int b = t / TPB, ti = t - b * TPB;
            v4f* outb = out4 + (size_t)b * COUT * PLANE4 + (size_t)ti * (TCELLS / 4) + xg;
            #pragma unroll
            for (int cc = 0; cc < 4; ++cc) {
                const int c = cc * 16 + chi;
                const v4f v = *(const v4f*)&lds[buf][c * LSTR + 4 * xg];
                __builtin_nontemporal_store(v, &outb[(size_t)c * PLANE4]);
            }
        }

        if (!have_next) break;
        t = t1; t1 = t2;
        w_cur = w_nxt; w_nxt = w2;
        #pragma unroll
        for (int k = 0; k < 4; ++k) r[k] = rn[k];
        buf ^= 1;
    }
}

extern "C" void kernel_launch(void* const* d_in, const int* in_sizes, int n_in,
                              void* d_out, int out_size, void* d_ws, size_t ws_size,
                              hipStream_t stream) {
    const float* pillars = (const float*)d_in[0];
    const int*   coors   = (const int*)d_in[1];
    const int*   nums    = (const int*)d_in[2];
    const float* W       = (const float*)d_in[3];
    const float* gamma   = (const float*)d_in[4];
    const float* beta    = (const float*)d_in[5];
    const float* rmean   = (const float*)d_in[6];
    const float* rvar    = (const float*)d_in[7];
    float* out = (float*)d_out;

    const int M = in_sizes[2];
    int*   winner = (int*)d_ws;                      // (4,496,432) = 3.43 MB
    float* pooled = (float*)((char*)d_ws + (size_t)BN * CELLS_B * sizeof(int)); // (M,64)

    (void)hipMemsetAsync(winner, 0xFF, (size_t)BN * CELLS_B * sizeof(int), stream);

    winner_kernel<<<(M + 255) / 256, 256, 0, stream>>>(coors, winner, M);
    pillar_compute<<<(M + 3) / 4, 256, 0, stream>>>(
        pillars, coors, nums, W, gamma, beta, rmean, rvar, winner, pooled, M);

    canvas_kernel<<<CBLOCKS, CTHREADS, 0, stream>>>(winner, pooled, (v4f*)out);
}

// Round 8
// 297.433 us; speedup vs baseline: 1.0232x; 1.0232x over previous
//
#include <hip/hip_runtime.h>

#define XL 432
#define YL 496
#define CELLS_B (YL * XL)     // 214272 = 256 * 837 cells per batch
#define PLANE4 (CELLS_B / 4)  // 53568 float4-groups per (b,c) plane
#define BN 4
#define COUT 64
#define PP 32

// canvas: tile = 256 contiguous cells, channel-group = 8 channels
#define TCELLS 256
#define TPB (CELLS_B / TCELLS)   // 837 tiles per batch (exact)
#define CG 8                     // channels per block
#define NCG (COUT / CG)          // 8 channel groups
#define LSTR 264                 // LDS cell-stride (dwords), 264%32=8

typedef float v4f __attribute__((ext_vector_type(4)));

// Pass 1: resolve scatter collisions — highest pillar index wins (numpy
// last-write-wins semantics for duplicate (b,y,x) cells).
__global__ __launch_bounds__(256) void winner_kernel(const int* __restrict__ coors,
                                                     int* __restrict__ winner, int M) {
    int m = blockIdx.x * blockDim.x + threadIdx.x;
    if (m >= M) return;
    const int4 c = ((const int4*)coors)[m];
    if (c.w < 0 || c.w >= XL || c.z < 0 || c.z >= YL) return;
    atomicMax(&winner[(c.x * YL + c.z) * XL + c.w], m);
}

// Pass 2 (unchanged): folded 9->64 matvec + BN + ReLU + max-pool.
__global__ __launch_bounds__(256) void pillar_compute(
    const float* __restrict__ pillars, const int* __restrict__ coors,
    const int* __restrict__ nums, const float* __restrict__ W,
    const float* __restrict__ gamma, const float* __restrict__ beta,
    const float* __restrict__ rmean, const float* __restrict__ rvar,
    const int* __restrict__ winner, float* __restrict__ pooled, int M) {
    const int pb   = threadIdx.x >> 6;
    const int lane = threadIdx.x & 63;
    const int m    = blockIdx.x * 4 + pb;

    __shared__ float4 pts[4][PP];

    if (m < M && lane < PP) {
        pts[pb][lane] = ((const float4*)pillars)[m * PP + lane];
    }
    __syncthreads();
    if (m >= M) return;

    const int4 co = ((const int4*)coors)[m];
    const int x = co.w, y = co.z;
    if (x < 0 || x >= XL || y < 0 || y >= YL) return;
    if (winner[(co.x * YL + y) * XL + x] != m) return;

    int num = nums[m];
    if (num < 1) num = 1;
    if (num > PP) num = PP;

    const float scale = gamma[lane] * rsqrtf(rvar[lane] + 1e-3f);
    const float bias  = beta[lane] - rmean[lane] * scale;

    const float w0 = W[lane * 9 + 0], w1 = W[lane * 9 + 1], w2 = W[lane * 9 + 2];
    const float w3 = W[lane * 9 + 3], w4 = W[lane * 9 + 4], w5 = W[lane * 9 + 5];
    const float w6 = W[lane * 9 + 6], w7 = W[lane * 9 + 7], w8 = W[lane * 9 + 8];
    const float cwx = w0 + w4 + w7, cwy = w1 + w5 + w8, cwz = w2 + w6, cww = w3;

    float sx = 0.f, sy = 0.f, sz = 0.f;
    float dmax = -3.0e38f, dmin = 3.0e38f;
    for (int p = 0; p < num; ++p) {
        const float4 q = pts[pb][p];
        sx += q.x; sy += q.y; sz += q.z;
        const float d = q.x * cwx + q.y * cwy + q.z * cwz + q.w * cww;
        dmax = fmaxf(dmax, d);
        dmin = fminf(dmin, d);
    }
    const float inv = 1.0f / (float)num;
    const float xc = (float)x * 0.16f + 0.08f;
    const float yc = (float)y * 0.16f + (0.08f - 39.68f);
    const float C0 = sx * inv * w4 + sy * inv * w5 + sz * inv * w6
                   + xc * w7 + yc * w8;

    const float sel = (scale >= 0.f) ? dmax : dmin;
    float v = (sel - C0) * scale + bias;
    if (num < PP) v = fmaxf(v, bias);
    pooled[m * COUT + lane] = fmaxf(v, 0.f);
}

// Pass 3: dense canvas write, channel-partitioned for store-address
// locality. Block = (tile of 256 contiguous cells [x-fastest grid dim],
// channel-group of 8, batch). At any instant the whole GPU writes within
// ~8 planes x a few KB — page/translation working set like the rocclr
// fill's, unlike the previous all-64-plane blocks.
// Phase 1: 1 thread/cell: winner + 32B pooled chunk -> LDS[ch][cell].
// Phase 2: thread (chi=t>>5, xg=t&31) stores f4 at xg, xg+32 of its
// channel's 1KB plane-run (full lines, 2 planes per wave-store).
__global__ __launch_bounds__(256) void canvas_kernel(
    const int* __restrict__ winner,     // (BN, YL, XL)
    const float* __restrict__ pooled,   // (M, 64)
    v4f* __restrict__ out4) {           // (BN, 64, PLANE4)
    __shared__ float lds[CG * LSTR];    // 8448 B

    const int tile = blockIdx.x;        // 0..836   (fastest -> locality)
    const int cg   = blockIdx.y;        // 0..7
    const int b    = blockIdx.z;        // 0..3
    const int t    = threadIdx.x;

    // ---- phase 1: gather this channel-chunk of each cell's winner row ----
    {
        const int cell = t;             // 0..255
        const int w = winner[b * CELLS_B + tile * TCELLS + cell];
        float4 r0, r1;
        if (w >= 0) {
            const float4* row = (const float4*)(pooled + (size_t)w * COUT + cg * CG);
            r0 = row[0];
            r1 = row[1];
        } else {
            r0 = make_float4(0.f, 0.f, 0.f, 0.f);
            r1 = make_float4(0.f, 0.f, 0.f, 0.f);
        }
        lds[0 * LSTR + cell] = r0.x;
        lds[1 * LSTR + cell] = r0.y;
        lds[2 * LSTR + cell] = r0.z;
        lds[3 * LSTR + cell] = r0.w;
        lds[4 * LSTR + cell] = r1.x;
        lds[5 * LSTR + cell] = r1.y;
        lds[6 * LSTR + cell] = r1.z;
        lds[7 * LSTR + cell] = r1.w;
    }
    __syncthreads();

    // ---- phase 2: contiguous 1KB run per channel, NT full-line stores ----
    {
        const int chi = t >> 5;         // 0..7  (channel within group)
        const int xg  = t & 31;         // 0..31 (f4 within 64-f4 tile run)
        const int c   = cg * CG + chi;
        v4f* outp = out4 + (size_t)(b * COUT + c) * PLANE4 + (size_t)tile * (TCELLS / 4);
        const v4f v0 = *(const v4f*)&lds[chi * LSTR + 4 * xg];
        const v4f v1 = *(const v4f*)&lds[chi * LSTR + 4 * (xg + 32)];
        __builtin_nontemporal_store(v0, &outp[xg]);
        __builtin_nontemporal_store(v1, &outp[xg + 32]);
    }
}

extern "C" void kernel_launch(void* const* d_in, const int* in_sizes, int n_in,
                              void* d_out, int out_size, void* d_ws, size_t ws_size,
                              hipStream_t stream) {
    const float* pillars = (const float*)d_in[0];
    const int*   coors   = (const int*)d_in[1];
    const int*   nums    = (const int*)d_in[2];
    const float* W       = (const float*)d_in[3];
    const float* gamma   = (const float*)d_in[4];
    const float* beta    = (const float*)d_in[5];
    const float* rmean   = (const float*)d_in[6];
    const float* rvar    = (const float*)d_in[7];
    float* out = (float*)d_out;

    const int M = in_sizes[2];
    int*   winner = (int*)d_ws;                      // (4,496,432) = 3.43 MB
    float* pooled = (float*)((char*)d_ws + (size_t)BN * CELLS_B * sizeof(int)); // (M,64)

    (void)hipMemsetAsync(winner, 0xFF, (size_t)BN * CELLS_B * sizeof(int), stream);

    winner_kernel<<<(M + 255) / 256, 256, 0, stream>>>(coors, winner, M);
    pillar_compute<<<(M + 3) / 4, 256, 0, stream>>>(
        pillars, coors, nums, W, gamma, beta, rmean, rvar, winner, pooled, M);

    dim3 cgrid(TPB, NCG, BN);           // tile fastest -> store locality
    canvas_kernel<<<cgrid, 256, 0, stream>>>(winner, pooled, (v4f*)out);
}